// Round 10
// baseline (297.067 us; speedup 1.0000x reference)
//
#include <hip/hip_runtime.h>
#include <hip/hip_bf16.h>
#include <math.h>

// ---------- types ----------
typedef __attribute__((ext_vector_type(8))) short bf16x8;
typedef __attribute__((ext_vector_type(4))) float f32x4;

#define MFMA16(a, b, c) __builtin_amdgcn_mfma_f32_16x16x32_bf16((a), (b), (c), 0, 0, 0)

static __device__ __forceinline__ float fast_exp2(float x) { return __builtin_amdgcn_exp2f(x); }

static __device__ __forceinline__ unsigned short f2bf(float f) {
  __hip_bfloat16 h = __float2bfloat16(f);
  unsigned short u;
  __builtin_memcpy(&u, &h, 2);
  return u;
}
static __device__ __forceinline__ float bf2f(unsigned short u) {
  unsigned int x = ((unsigned int)u) << 16;
  float f;
  __builtin_memcpy(&f, &x, 4);
  return f;
}

// ---------- merged prep: casts + wsmall + rope table + wg transpose ----------
static __device__ __forceinline__ void cast8(const float* __restrict__ src,
                                             unsigned short* __restrict__ dst, int blk, int tid) {
  int i = (blk * 256 + tid) * 8;
  float4 a = *(const float4*)(src + i);
  float4 b = *(const float4*)(src + i + 4);
  union { unsigned short u[8]; bf16x8 v; } o;
  o.u[0] = f2bf(a.x); o.u[1] = f2bf(a.y); o.u[2] = f2bf(a.z); o.u[3] = f2bf(a.w);
  o.u[4] = f2bf(b.x); o.u[5] = f2bf(b.y); o.u[6] = f2bf(b.z); o.u[7] = f2bf(b.w);
  *(bf16x8*)(dst + i) = o.v;
}

__global__ __launch_bounds__(256) void prep(const float* __restrict__ x, const float* __restrict__ Wq,
                                            const float* __restrict__ Wout, const float* __restrict__ Wkv,
                                            const float* __restrict__ Wkvh, const float* __restrict__ Wg,
                                            unsigned short* __restrict__ x_bf, unsigned short* __restrict__ wq_bf,
                                            unsigned short* __restrict__ wout_bf, unsigned short* __restrict__ wsm_bf,
                                            float2* __restrict__ cs, float* __restrict__ wgt) {
  int bid = blockIdx.x, tid = threadIdx.x;
  if (bid < 4096) {
    cast8(x, x_bf, bid, tid);
  } else if (bid < 6144) {
    cast8(Wq, wq_bf, bid - 4096, tid);
  } else if (bid < 8192) {
    cast8(Wout, wout_bf, bid - 6144, tid);
  } else if (bid < 8576) {
    int row = bid - 8192;
    int c = tid * 8;
    const float* src = nullptr;
    if (row < 256) src = Wkv + (size_t)row * 2048;
    else if (row < 288) src = Wkvh + (size_t)(row - 256) * 2048;
    union { unsigned short u[8]; bf16x8 v; } o;
    if (src) {
      float4 a = *(const float4*)(src + c);
      float4 b = *(const float4*)(src + c + 4);
      o.u[0] = f2bf(a.x); o.u[1] = f2bf(a.y); o.u[2] = f2bf(a.z); o.u[3] = f2bf(a.w);
      o.u[4] = f2bf(b.x); o.u[5] = f2bf(b.y); o.u[6] = f2bf(b.z); o.u[7] = f2bf(b.w);
    } else {
      for (int j = 0; j < 8; j++) o.u[j] = 0;
    }
    *(bf16x8*)(wsm_bf + (size_t)row * 2048 + c) = o.v;
  } else if (bid < 9088) {
    int i = (bid - 8576) * 256 + tid;
    int f = i & 63, n = i >> 6;
    float inv = powf(10000.0f, -(float)(2 * f) / 128.0f);
    float ang = (float)n * inv;
    cs[i] = make_float2(cosf(ang), sinf(ang));
  } else {
    int i = (bid - 9088) * 256 + tid;
    int oc = i >> 11, k = i & 2047;
    wgt[(size_t)k * 32 + oc] = Wg[i];
  }
}

// ---------- shared GEMM body: m97 2-barrier structure, BK=64, XCD swizzle ----------
// MODE 0: C fp32 (ldc).  MODE 1: merged q+small — cols<2048 scatter bf16 to q_r, cols>=2048 fp32 small_out.
template <int MODE>
static __device__ __forceinline__ void gemm_body(const unsigned short* __restrict__ A,
                                                 const unsigned short* __restrict__ B,
                                                 float* __restrict__ Cf,
                                                 unsigned short* __restrict__ Cb,
                                                 int K, int ldc, int lin, int nbx, int cpx) {
  __shared__ unsigned short As[128 * 64];
  __shared__ unsigned short Bs[128 * 64];
  int tid = threadIdx.x;
  int wave = tid >> 6, lane = tid & 63, l15 = lane & 15, lg = lane >> 4;
  int wr = wave >> 1, wc = wave & 1;
  int swz = (lin & 7) * cpx + (lin >> 3);
  int bx = swz % nbx, by = swz / nbx;
  int row0 = by * 128, col0 = bx * 128;
  f32x4 acc[4][4];
#pragma unroll
  for (int m = 0; m < 4; m++)
#pragma unroll
    for (int n = 0; n < 4; n++) acc[m][n] = (f32x4){0.f, 0.f, 0.f, 0.f};

  for (int k0 = 0; k0 < K; k0 += 64) {
#pragma unroll
    for (int c = 0; c < 4; c++) {
      int chunk = c * 256 + tid;            // 0..1023 : 128 rows x 8 chunks of 8 shorts
      int r = chunk >> 3, kk = (chunk & 7) * 8;
      __builtin_amdgcn_global_load_lds(
          (const __attribute__((address_space(1))) void*)(A + (size_t)(row0 + r) * K + k0 + kk),
          (__attribute__((address_space(3))) void*)(As + ((size_t)c * 256 + wave * 64) * 8), 16, 0, 0);
      __builtin_amdgcn_global_load_lds(
          (const __attribute__((address_space(1))) void*)(B + (size_t)(col0 + r) * K + k0 + kk),
          (__attribute__((address_space(3))) void*)(Bs + ((size_t)c * 256 + wave * 64) * 8), 16, 0, 0);
    }
    __syncthreads();
    bf16x8 af[4][2], bfr[4][2];
#pragma unroll
    for (int m = 0; m < 4; m++)
#pragma unroll
      for (int ks = 0; ks < 2; ks++)
        af[m][ks] = *(const bf16x8*)&As[(wr * 64 + m * 16 + l15) * 64 + ks * 32 + lg * 8];
#pragma unroll
    for (int n = 0; n < 4; n++)
#pragma unroll
      for (int ks = 0; ks < 2; ks++)
        bfr[n][ks] = *(const bf16x8*)&Bs[(wc * 64 + n * 16 + l15) * 64 + ks * 32 + lg * 8];
#pragma unroll
    for (int ks = 0; ks < 2; ks++)
#pragma unroll
      for (int m = 0; m < 4; m++)
#pragma unroll
        for (int n = 0; n < 4; n++) acc[m][n] = MFMA16(af[m][ks], bfr[n][ks], acc[m][n]);
    __syncthreads();
  }

  if (MODE == 0 || col0 >= 2048) {
#pragma unroll
    for (int m = 0; m < 4; m++) {
      int row_b = row0 + wr * 64 + m * 16 + lg * 4;
#pragma unroll
      for (int n = 0; n < 4; n++) {
        int col = col0 + wc * 64 + n * 16 + l15;
        int cw = (MODE == 0) ? col : (col - 2048);
#pragma unroll
        for (int j = 0; j < 4; j++) {
          Cf[(size_t)(row_b + j) * ldc + cw] = acc[m][n][j];
        }
      }
    }
  } else {
#pragma unroll
    for (int m = 0; m < 4; m++) {
      int row_b = row0 + wr * 64 + m * 16 + lg * 4;
#pragma unroll
      for (int n = 0; n < 4; n++) {
        int col = col0 + wc * 64 + n * 16 + l15;
        int h = col >> 7, d = col & 127;
#pragma unroll
        for (int j = 0; j < 4; j++) {
          int row = row_b + j;
          int b = row >> 11, nn = row & 2047;
          Cb[(((size_t)b * 16 + h) * 2048 + nn) * 128 + d] = f2bf(acc[m][n][j]);
        }
      }
    }
  }
}

// ---------- fused: merged q+small GEMM (blocks 0..607) + gproj (blocks 608..1119) ----------
__global__ __launch_bounds__(256) void gemm_q_gproj(const unsigned short* __restrict__ A,
                                                    const unsigned short* __restrict__ B,
                                                    float* __restrict__ small_out,
                                                    unsigned short* __restrict__ q_r,
                                                    const float* __restrict__ x,
                                                    const float* __restrict__ Wgt,
                                                    float* __restrict__ lsg_t) {
  if (blockIdx.x >= 608) {
    // gproj: lsg_t[b][ch][n] = log_sigmoid(x @ Wg^T)
    int tid = (blockIdx.x - 608) * 256 + threadIdx.x;  // 4096*32
    int tok = tid >> 5, oc = tid & 31;
    const float* xr = x + (size_t)tok * 2048;
    float acc = 0.f;
    for (int k = 0; k < 2048; k += 4) {
      float4 a = *(const float4*)(xr + k);
      acc += a.x * Wgt[(size_t)k * 32 + oc] + a.y * Wgt[(size_t)(k + 1) * 32 + oc] +
             a.z * Wgt[(size_t)(k + 2) * 32 + oc] + a.w * Wgt[(size_t)(k + 3) * 32 + oc];
    }
    float ls = (acc >= 0.f) ? -log1pf(expf(-acc)) : acc - log1pf(expf(acc));
    int b = tok >> 11, n = tok & 2047;
    lsg_t[((size_t)(b * 32 + oc)) * 2048 + n] = ls;
    return;
  }
  gemm_body<1>(A, B, small_out, q_r, 2048, 384, blockIdx.x, 19, 76);
}

// ---------- out GEMM ----------
__global__ __launch_bounds__(256) void gemm_out(const unsigned short* __restrict__ A,
                                                const unsigned short* __restrict__ B,
                                                float* __restrict__ C) {
  gemm_body<0>(A, B, C, nullptr, 2048, 2048, (int)(blockIdx.y * 16 + blockIdx.x), 16, 64);
}

// ---------- scan v3: 64 blocks (b,ch), 256 thr x 8 toks, shfl wave-scan ----------
__global__ __launch_bounds__(256) void scan_kernel(const float* __restrict__ lsg_t,
                                                   const float* __restrict__ so,
                                                   float* __restrict__ khvh) {
  int b = blockIdx.x >> 5, ch = blockIdx.x & 31;
  int t = threadIdx.x, lane = t & 63, wv = t >> 6;
  const float* L = lsg_t + ((size_t)(b * 32 + ch)) * 2048 + t * 8;
  float ls[8], v[8];
  float4 a = *(const float4*)L, c = *(const float4*)(L + 4);
  ls[0] = a.x; ls[1] = a.y; ls[2] = a.z; ls[3] = a.w;
  ls[4] = c.x; ls[5] = c.y; ls[6] = c.z; ls[7] = c.w;
  const float* V = so + ((size_t)(b * 2048 + t * 8)) * 384 + 256 + ch;
#pragma unroll
  for (int j = 0; j < 8; j++) v[j] = V[(size_t)j * 384];
  float run = 0.f;
#pragma unroll
  for (int j = 0; j < 8; j++) run += ls[j];
  float incl = run;
#pragma unroll
  for (int off = 1; off < 64; off <<= 1) {
    float nv = __shfl_up(incl, off);
    if (lane >= off) incl += nv;
  }
  __shared__ float ws[2][4];
  if (lane == 63) ws[0][wv] = incl;
  __syncthreads();
  float wbase = 0.f;
#pragma unroll
  for (int w = 0; w < 4; w++) wbase += (w < wv) ? ws[0][w] : 0.f;
  float baseA = wbase + incl - run;
  float lf = baseA, s = 0.f;
#pragma unroll
  for (int j = 0; j < 8; j++) { s += v[j] * __expf(lf); lf += ls[j]; }
  float incl2 = s;
#pragma unroll
  for (int off = 1; off < 64; off <<= 1) {
    float nv = __shfl_up(incl2, off);
    if (lane >= off) incl2 += nv;
  }
  if (lane == 63) ws[1][wv] = incl2;
  __syncthreads();
  float wbase2 = 0.f;
#pragma unroll
  for (int w = 0; w < 4; w++) wbase2 += (w < wv) ? ws[1][w] : 0.f;
  float base2 = wbase2 + incl2 - s;
  lf = baseA; s = base2;
  float* O = khvh + ((size_t)(b * 2048 + t * 8)) * 32 + ch;
#pragma unroll
  for (int j = 0; j < 8; j++) { s += v[j] * __expf(lf); lf += ls[j]; O[(size_t)j * 32] = s; }
}

// ---------- build_kv2: merged k_r build (+rope) and v_t transposed build ----------
__global__ __launch_bounds__(256) void build_kv2(const float* __restrict__ so,
                                                 const float* __restrict__ khvh,
                                                 const float2* __restrict__ cs,
                                                 unsigned short* __restrict__ k_r,
                                                 unsigned short* __restrict__ v_t) {
  int ntb = blockIdx.x, bh = blockIdx.y;
  int b = bh >> 4, h = bh & 15;
  int tok0 = b * 2048 + ntb * 64;
  int n0 = ntb * 64;
  __shared__ float khs[64], vhs[64];
  __shared__ unsigned short Vt_s[64 * 132];
  int t = threadIdx.x;
  if (t < 64) {
    khs[t] = khvh[(size_t)(tok0 + t) * 32 + h];
    vhs[t] = khvh[(size_t)(tok0 + t) * 32 + 16 + h];
  }
  __syncthreads();
#pragma unroll
  for (int c = 0; c < 4; c++) {
    int idx = c * 256 + t;
    int r = idx >> 4, q4 = (idx & 15) * 4;
    const float* sop = so + (size_t)(tok0 + r) * 384;
    float4 k1 = *(const float4*)(sop + q4);
    float4 k2 = *(const float4*)(sop + 64 + q4);
    float kh = khs[r];
    int n = n0 + r;
    union { unsigned short u[4]; uint2 v2; } o1, o2;
#pragma unroll
    for (int j = 0; j < 4; j++) {
      float2 cc = cs[(n << 6) + q4 + j];
      float av = ((const float*)&k1)[j], bv = ((const float*)&k2)[j];
      o1.u[j] = f2bf((av * cc.x - bv * cc.y) * kh);
      o2.u[j] = f2bf((bv * cc.x + av * cc.y) * kh);
    }
    size_t off = ((size_t)bh * 2048 + n) * 128 + q4;
    *(uint2*)(k_r + off) = o1.v2;
    *(uint2*)(k_r + off + 64) = o2.v2;
  }
#pragma unroll
  for (int c = 0; c < 8; c++) {
    int idx = c * 256 + t;
    int r = idx >> 5, d4 = (idx & 31) * 4;
    const float* sop = so + (size_t)(tok0 + r) * 384 + 128;
    float4 v = *(const float4*)(sop + d4);
    float vh = vhs[r];
    union { unsigned short u[4]; uint2 v2; } ov;
#pragma unroll
    for (int j = 0; j < 4; j++) ov.u[j] = f2bf(((const float*)&v)[j] * vh);
    *(uint2*)&Vt_s[r * 132 + d4] = ov.v2;
  }
  __syncthreads();
#pragma unroll
  for (int c = 0; c < 4; c++) {
    int idx = c * 256 + t;
    int d = idx >> 3, c8 = (idx & 7) * 8;
    union { unsigned short u[8]; bf16x8 v; } o;
#pragma unroll
    for (int j = 0; j < 8; j++) o.u[j] = Vt_s[(c8 + j) * 132 + d];
    *(bf16x8*)(v_t + ((size_t)bh * 128 + d) * 2048 + n0 + c8) = o.v;
  }
}

// ---------- flash attention v4.2: Ps stride back to 72 ----------
__global__ __launch_bounds__(256, 2) void flash_attn(const unsigned short* __restrict__ q_r,
                                                     const unsigned short* __restrict__ k_r,
                                                     const unsigned short* __restrict__ v_t,
                                                     const float2* __restrict__ cs,
                                                     unsigned short* __restrict__ o) {
  int lin = blockIdx.y * 16 + blockIdx.x;
  int swz = (lin & 7) * 64 + (lin >> 3);
  int bx = swz & 15, bh = swz >> 4;
  const unsigned short* Kg = k_r + (size_t)bh * 2048 * 128;
  const unsigned short* Vtg = v_t + (size_t)bh * 128 * 2048;
  __shared__ unsigned short Ks[2][64 * 128];
  __shared__ unsigned short VTs[2][128 * 64];
  __shared__ unsigned short Ps[4][16 * 72];
  int tid = threadIdx.x, wave = tid >> 6, lane = tid & 63, l15 = lane & 15, lg = lane >> 4;
  int sw = (l15 & 7) * 8;
  int b = bh >> 4, h = bh & 15;

  union { unsigned short u[8]; bf16x8 v; } onesu;
#pragma unroll
  for (int j = 0; j < 8; j++) onesu.u[j] = 0x3F80;
  const bf16x8 ones = onesu.v;

  int qtA = bx, qtB = 31 - bx;
  int qt = qtA;

  bf16x8 qf[4];
#define LOAD_Q()                                                                                   \
  {                                                                                                \
    const unsigned short* Qg = q_r + ((size_t)bh * 2048 + qt * 64) * 128;                          \
    int n = qt * 64 + wave * 16 + l15;                                                             \
    union { unsigned short u[8]; bf16x8 v; } r0, r1, r2, r3;                                       \
    r0.v = *(const bf16x8*)(Qg + (wave * 16 + l15) * 128 + 0 * 32 + lg * 8);                       \
    r1.v = *(const bf16x8*)(Qg + (wave * 16 + l15) * 128 + 1 * 32 + lg * 8);                       \
    r2.v = *(const bf16x8*)(Qg + (wave * 16 + l15) * 128 + 2 * 32 + lg * 8);                       \
    r3.v = *(const bf16x8*)(Qg + (wave * 16 + l15) * 128 + 3 * 32 + lg * 8);                       \
    union { unsigned short u[8]; bf16x8 v; } o0, o1, o2, o3;                                       \
    _Pragma("unroll") for (int j = 0; j < 8; j++) {                                                \
      float2 c0 = cs[(n << 6) + 0 * 32 + lg * 8 + j];                                              \
      float t1 = bf2f(r0.u[j]), t2 = bf2f(r2.u[j]);                                                \
      o0.u[j] = f2bf(t1 * c0.x - t2 * c0.y);                                                       \
      o2.u[j] = f2bf(t2 * c0.x + t1 * c0.y);                                                       \
      float2 c1 = cs[(n << 6) + 1 * 32 + lg * 8 + j];                                              \
      float s1 = bf2f(r1.u[j]), s2 = bf2f(r3.u[j]);                                                \
      o1.u[j] = f2bf(s1 * c1.x - s2 * c1.y);                                                       \
      o3.u[j] = f2bf(s2 * c1.x + s1 * c1.y);                                                       \
    }                                                                                              \
    qf[0] = o0.v; qf[1] = o1.v; qf[2] = o2.v; qf[3] = o3.v;                                        \
  }

  LOAD_Q();

  float m_r[4], l_r[4];
  f32x4 oacc[8];
#pragma unroll
  for (int j = 0; j < 4; j++) { m_r[j] = -INFINITY; l_r[j] = 0.f; }
#pragma unroll
  for (int db = 0; db < 8; db++) oacc[db] = (f32x4){0.f, 0.f, 0.f, 0.f};

  const float kscale = 0.12753102f;  // (1/sqrt(128)) * log2(e)
  const float THR = 11.0f;

#define STAGE(kt, bsel)                                                                           \
  {                                                                                               \
    int kti = (kt);                                                                               \
    int bs = (bsel);                                                                              \
    _Pragma("unroll") for (int c = 0; c < 4; c++) {                                               \
      int s = c * 256 + tid;                                                                      \
      int kr = s >> 4, kc = ((s & 15) ^ (kr & 7)) * 8;                                            \
      __builtin_amdgcn_global_load_lds(                                                           \
          (const __attribute__((address_space(1))) void*)(Kg + (size_t)(kti * 64 + kr) * 128 + kc),\
          (__attribute__((address_space(3))) void*)(&Ks[bs][(c * 256 + wave * 64) * 8]), 16, 0, 0);\
      int vr = s >> 3, vc = ((s & 7) ^ (vr & 7)) * 8;                                             \
      __builtin_amdgcn_global_load_lds(                                                           \
          (const __attribute__((address_space(1))) void*)(Vtg + (size_t)vr * 2048 + kti * 64 + vc),\
          (__attribute__((address_space(3))) void*)(&VTs[bs][(c * 256 + wave * 64) * 8]), 16, 0, 0);\
    }                                                                                             \
  }

  STAGE(0, 0);
  __syncthreads();

  for (int s = 0; s < 33; ++s) {
    int nb = s & 1;
    if (s + 1 < 33) {
      int nk = (s + 1 <= qtA) ? (s + 1) : (s + 1 - (qtA + 1));
      STAGE(nk, nb ^ 1);
    }
    int kt = (s <= qtA) ? s : (s - (qtA + 1));
    bool diag = (s == qtA) || (s == 32);
    int qrow0 = qt * 64 + wave * 16 + lg * 4;

    f32x4 sc[4];
#pragma unroll
    for (int cb = 0; cb < 4; cb++) sc[cb] = (f32x4){0.f, 0.f, 0.f, 0.f};
    __builtin_amdgcn_s_setprio(1);
#pragma unroll
    for (int kk = 0; kk < 4; kk++) {
#pragma unroll
      for (int cb = 0; cb < 4; cb++) {
        bf16x8 kf = *(const bf16x8*)&Ks[nb][(cb * 16 + l15) * 128 + ((kk * 32 + lg * 8) ^ sw)];
        sc[cb] = MFMA16(qf[kk], kf, sc[cb]);
      }
    }
    __builtin_amdgcn_s_setprio(0);
    if (diag) {
#pragma unroll
      for (int cb = 0; cb < 4; cb++) {
        int col = kt * 64 + cb * 16 + l15;
#pragma unroll
        for (int j = 0; j < 4; j++) {
          float v = sc[cb][j] * kscale;
          if (col > qrow0 + j) v = -INFINITY;
          sc[cb][j] = v;
        }
      }
    } else {
#pragma unroll
      for (int cb = 0; cb < 4; cb++)
#pragma unroll
        for (int j = 0; j < 4; j++) sc[cb][j] *= kscale;
    }
    float pm[4];
#pragma unroll
    for (int j = 0; j < 4; j++)
      pm[j] = fmaxf(fmaxf(sc[0][j], sc[1][j]), fmaxf(sc[2][j], sc[3][j]));
    bool grow = !__all((pm[0] <= m_r[0] + THR) & (pm[1] <= m_r[1] + THR) &
                       (pm[2] <= m_r[2] + THR) & (pm[3] <= m_r[3] + THR));
    if (grow) {
#pragma unroll
      for (int off = 1; off < 16; off <<= 1) {
#pragma unroll
        for (int j = 0; j < 4; j++) pm[j] = fmaxf(pm[j], __shfl_xor(pm[j], off));
      }
#pragma unroll
      for (int j = 0; j < 4; j++) {
        float mn = fmaxf(m_r[j], pm[j]);
        float corr = fast_exp2(m_r[j] - mn);
        m_r[j] = mn;
        l_r[j] *= corr;
#pragma unroll
        for (int db = 0; db < 8; db++) oacc[db][j] *= corr;
      }
    }
#pragma unroll
    for (int cb = 0; cb < 4; cb++)
#pragma unroll
      for (int j = 0; j < 4; j++)
        Ps[wave][(lg * 4 + j) * 72 + cb * 16 + l15] = f2bf(fast_exp2(sc[cb][j] - m_r[j]));
    f32x4 sacc = (f32x4){0.f, 0.f, 0.f, 0.f};
    __builtin_amdgcn_s_setprio(1);
#pragma unroll
    for (int kc = 0; kc < 2; kc++) {
      bf16x8 pa = *(const bf16x8*)&Ps[wave][l15 * 72 + kc * 32 + lg * 8];
      sacc = MFMA16(pa, ones, sacc);
#pragma unroll
      for (int db = 0; db < 8; db++) {
        bf16x8 vb = *(const bf16x8*)&VTs[nb][(db * 16 + l15) * 64 + ((kc * 32 + lg * 8) ^ sw)];
        oacc[db] = MFMA16(pa, vb, oacc[db]);
      }
    }
    __builtin_amdgcn_s_setprio(0);
#pragma unroll
    for (int j = 0; j < 4; j++) l_r[j] += sacc[j];
    __syncthreads();

    if (s == qtA) {
      int qrow_e = qt * 64 + wave * 16 + lg * 4;
#pragma unroll
      for (int db = 0; db < 8; db++) {
        int d = db * 16 + l15;
#pragma unroll
        for (int j = 0; j < 4; j++) {
          float val = oacc[db][j] / l_r[j];
          o[((size_t)(b * 2048 + qrow_e + j)) * 2048 + h * 128 + d] = f2bf(val);
        }
      }
      qt = qtB;
      LOAD_Q();
#pragma unroll
      for (int j = 0; j < 4; j++) { m_r[j] = -INFINITY; l_r[j] = 0.f; }
#pragma unroll
      for (int db = 0; db < 8; db++) oacc[db] = (f32x4){0.f, 0.f, 0.f, 0.f};
    }
  }
  int qrow_e = qt * 64 + wave * 16 + lg * 4;
#pragma unroll
  for (int db = 0; db < 8; db++) {
    int d = db * 16 + l15;
#pragma unroll
    for (int j = 0; j < 4; j++) {
      float val = oacc[db][j] / l_r[j];
      o[((size_t)(b * 2048 + qrow_e + j)) * 2048 + h * 128 + d] = f2bf(val);
    }
  }
#undef STAGE
#undef LOAD_Q
}

// ---------- host launch ----------
extern "C" void kernel_launch(void* const* d_in, const int* in_sizes, int n_in,
                              void* d_out, int out_size, void* d_ws, size_t ws_size,
                              hipStream_t stream) {
  (void)in_sizes; (void)n_in; (void)out_size; (void)ws_size;
  const float* x    = (const float*)d_in[0];
  const float* Wq   = (const float*)d_in[1];
  const float* Wkv  = (const float*)d_in[2];
  const float* Wkvh = (const float*)d_in[3];
  const float* Wg   = (const float*)d_in[4];
  const float* Wout = (const float*)d_in[5];
  float* out = (float*)d_out;

  char* ws = (char*)d_ws;
  size_t off = 0;
  auto alloc = [&](size_t bytes) -> void* {
    void* p = ws + off;
    off += (bytes + 255) & ~(size_t)255;
    return p;
  };
  unsigned short* x_bf    = (unsigned short*)alloc(4096ull * 2048 * 2);
  unsigned short* wq_bf   = (unsigned short*)alloc(2048ull * 2048 * 2);   // must stay adjacent to wsm_bf
  unsigned short* wsm_bf  = (unsigned short*)alloc(384ull * 2048 * 2);    // rows 2048..2431 of merged B
  unsigned short* wout_bf = (unsigned short*)alloc(2048ull * 2048 * 2);
  unsigned short* q_r     = (unsigned short*)alloc(4096ull * 2048 * 2);
  unsigned short* k_r     = (unsigned short*)alloc(4096ull * 2048 * 2);
  unsigned short* o_bf    = (unsigned short*)alloc(4096ull * 2048 * 2);
  float* small_out        = (float*)alloc(4096ull * 384 * 4);
  float* lsg_t            = (float*)alloc(64ull * 2048 * 4);
  float* khvh             = (float*)alloc(4096ull * 32 * 4);
  float2* cs              = (float2*)alloc(2048ull * 64 * 8);
  float* wgt              = (float*)alloc(2048ull * 32 * 4);
  unsigned short* v_t     = x_bf;  // x_bf dead after merged GEMM

  prep<<<9344, 256, 0, stream>>>(x, Wq, Wout, Wkv, Wkvh, Wg, x_bf, wq_bf, wout_bf, wsm_bf, cs, wgt);
  gemm_q_gproj<<<1120, 256, 0, stream>>>(x_bf, wq_bf, small_out, q_r, x, wgt, lsg_t);
  scan_kernel<<<64, 256, 0, stream>>>(lsg_t, small_out, khvh);
  build_kv2<<<dim3(32, 32), 256, 0, stream>>>(small_out, khvh, cs, k_r, v_t);
  flash_attn<<<dim3(16, 32), 256, 0, stream>>>(q_r, k_r, v_t, cs, o_bf);
  gemm_out<<<dim3(16, 32), 256, 0, stream>>>(o_bf, wout_bf, out);
}

// Round 11
// 282.442 us; speedup vs baseline: 1.0518x; 1.0518x over previous
//
#include <hip/hip_runtime.h>
#include <hip/hip_bf16.h>
#include <math.h>

// ---------- types ----------
typedef __attribute__((ext_vector_type(8))) short bf16x8;
typedef __attribute__((ext_vector_type(4))) float f32x4;

#define MFMA16(a, b, c) __builtin_amdgcn_mfma_f32_16x16x32_bf16((a), (b), (c), 0, 0, 0)

static __device__ __forceinline__ float fast_exp2(float x) { return __builtin_amdgcn_exp2f(x); }

static __device__ __forceinline__ unsigned short f2bf(float f) {
  __hip_bfloat16 h = __float2bfloat16(f);
  unsigned short u;
  __builtin_memcpy(&u, &h, 2);
  return u;
}
static __device__ __forceinline__ float bf2f(unsigned short u) {
  unsigned int x = ((unsigned int)u) << 16;
  float f;
  __builtin_memcpy(&f, &x, 4);
  return f;
}

// ---------- merged prep: casts + wsmall + rope table + wg transpose ----------
static __device__ __forceinline__ void cast8(const float* __restrict__ src,
                                             unsigned short* __restrict__ dst, int blk, int tid) {
  int i = (blk * 256 + tid) * 8;
  float4 a = *(const float4*)(src + i);
  float4 b = *(const float4*)(src + i + 4);
  union { unsigned short u[8]; bf16x8 v; } o;
  o.u[0] = f2bf(a.x); o.u[1] = f2bf(a.y); o.u[2] = f2bf(a.z); o.u[3] = f2bf(a.w);
  o.u[4] = f2bf(b.x); o.u[5] = f2bf(b.y); o.u[6] = f2bf(b.z); o.u[7] = f2bf(b.w);
  *(bf16x8*)(dst + i) = o.v;
}

__global__ __launch_bounds__(256) void prep(const float* __restrict__ x, const float* __restrict__ Wq,
                                            const float* __restrict__ Wout, const float* __restrict__ Wkv,
                                            const float* __restrict__ Wkvh, const float* __restrict__ Wg,
                                            unsigned short* __restrict__ x_bf, unsigned short* __restrict__ wq_bf,
                                            unsigned short* __restrict__ wout_bf, unsigned short* __restrict__ wsm_bf,
                                            float2* __restrict__ cs, float* __restrict__ wgt) {
  int bid = blockIdx.x, tid = threadIdx.x;
  if (bid < 4096) {
    cast8(x, x_bf, bid, tid);
  } else if (bid < 6144) {
    cast8(Wq, wq_bf, bid - 4096, tid);
  } else if (bid < 8192) {
    cast8(Wout, wout_bf, bid - 6144, tid);
  } else if (bid < 8576) {
    int row = bid - 8192;
    int c = tid * 8;
    const float* src = nullptr;
    if (row < 256) src = Wkv + (size_t)row * 2048;
    else if (row < 288) src = Wkvh + (size_t)(row - 256) * 2048;
    union { unsigned short u[8]; bf16x8 v; } o;
    if (src) {
      float4 a = *(const float4*)(src + c);
      float4 b = *(const float4*)(src + c + 4);
      o.u[0] = f2bf(a.x); o.u[1] = f2bf(a.y); o.u[2] = f2bf(a.z); o.u[3] = f2bf(a.w);
      o.u[4] = f2bf(b.x); o.u[5] = f2bf(b.y); o.u[6] = f2bf(b.z); o.u[7] = f2bf(b.w);
    } else {
      for (int j = 0; j < 8; j++) o.u[j] = 0;
    }
    *(bf16x8*)(wsm_bf + (size_t)row * 2048 + c) = o.v;
  } else if (bid < 9088) {
    int i = (bid - 8576) * 256 + tid;
    int f = i & 63, n = i >> 6;
    float inv = powf(10000.0f, -(float)(2 * f) / 128.0f);
    float ang = (float)n * inv;
    cs[i] = make_float2(cosf(ang), sinf(ang));
  } else {
    int i = (bid - 9088) * 256 + tid;
    int oc = i >> 11, k = i & 2047;
    wgt[(size_t)k * 32 + oc] = Wg[i];
  }
}

// ---------- lsg_t[b][ch][n] = log_sigmoid(x @ Wg^T), transposed write ----------
__global__ __launch_bounds__(256) void gproj(const float* __restrict__ x, const float* __restrict__ Wgt,
                                             float* __restrict__ lsg_t) {
  int tid = blockIdx.x * 256 + threadIdx.x;  // 4096*32
  int tok = tid >> 5, oc = tid & 31;
  const float* xr = x + (size_t)tok * 2048;
  float acc = 0.f;
  for (int k = 0; k < 2048; k += 4) {
    float4 a = *(const float4*)(xr + k);
    acc += a.x * Wgt[(size_t)k * 32 + oc] + a.y * Wgt[(size_t)(k + 1) * 32 + oc] +
           a.z * Wgt[(size_t)(k + 2) * 32 + oc] + a.w * Wgt[(size_t)(k + 3) * 32 + oc];
  }
  float ls = (acc >= 0.f) ? -log1pf(expf(-acc)) : acc - log1pf(expf(acc));
  int b = tok >> 11, n = tok & 2047;
  lsg_t[((size_t)(b * 32 + oc)) * 2048 + n] = ls;
}

// ---------- shared GEMM body: m97 2-barrier, BK=64, row-XOR LDS swizzle, XCD swizzle ----------
// LDS[r][sl] holds global col (sl ^ (r&7)); reader fetches slot (s ^ (R&7)). 2-way banks = free.
// MODE 0: C fp32 (ldc).  MODE 1: merged q+small — cols<2048 scatter bf16 to q_r, cols>=2048 fp32 small_out.
template <int MODE>
static __device__ __forceinline__ void gemm_body(const unsigned short* __restrict__ A,
                                                 const unsigned short* __restrict__ B,
                                                 float* __restrict__ Cf,
                                                 unsigned short* __restrict__ Cb,
                                                 int K, int ldc, int lin, int nbx, int cpx) {
  __shared__ unsigned short As[128 * 64];
  __shared__ unsigned short Bs[128 * 64];
  int tid = threadIdx.x;
  int wave = tid >> 6, lane = tid & 63, l15 = lane & 15, lg = lane >> 4;
  int wr = wave >> 1, wc = wave & 1;
  int swz = (lin & 7) * cpx + (lin >> 3);
  int bx = swz % nbx, by = swz / nbx;
  int row0 = by * 128, col0 = bx * 128;
  int rsw = l15 & 7;  // R&7 for all fragment rows (row bases are multiples of 16)
  f32x4 acc[4][4];
#pragma unroll
  for (int m = 0; m < 4; m++)
#pragma unroll
    for (int n = 0; n < 4; n++) acc[m][n] = (f32x4){0.f, 0.f, 0.f, 0.f};

  for (int k0 = 0; k0 < K; k0 += 64) {
#pragma unroll
    for (int c = 0; c < 4; c++) {
      int chunk = c * 256 + tid;            // 0..1023 : 128 rows x 8 slots of 8 shorts
      int r = chunk >> 3, sl = chunk & 7;
      int kk = (sl ^ (r & 7)) * 8;          // source pre-swizzle (involution)
      __builtin_amdgcn_global_load_lds(
          (const __attribute__((address_space(1))) void*)(A + (size_t)(row0 + r) * K + k0 + kk),
          (__attribute__((address_space(3))) void*)(As + ((size_t)c * 256 + wave * 64) * 8), 16, 0, 0);
      __builtin_amdgcn_global_load_lds(
          (const __attribute__((address_space(1))) void*)(B + (size_t)(col0 + r) * K + k0 + kk),
          (__attribute__((address_space(3))) void*)(Bs + ((size_t)c * 256 + wave * 64) * 8), 16, 0, 0);
    }
    __syncthreads();
    bf16x8 af[4][2], bfr[4][2];
#pragma unroll
    for (int m = 0; m < 4; m++)
#pragma unroll
      for (int ks = 0; ks < 2; ks++)
        af[m][ks] = *(const bf16x8*)&As[(wr * 64 + m * 16 + l15) * 64 + ((ks * 4 + lg) ^ rsw) * 8];
#pragma unroll
    for (int n = 0; n < 4; n++)
#pragma unroll
      for (int ks = 0; ks < 2; ks++)
        bfr[n][ks] = *(const bf16x8*)&Bs[(wc * 64 + n * 16 + l15) * 64 + ((ks * 4 + lg) ^ rsw) * 8];
#pragma unroll
    for (int ks = 0; ks < 2; ks++)
#pragma unroll
      for (int m = 0; m < 4; m++)
#pragma unroll
        for (int n = 0; n < 4; n++) acc[m][n] = MFMA16(af[m][ks], bfr[n][ks], acc[m][n]);
    __syncthreads();
  }

  if (MODE == 0 || col0 >= 2048) {
#pragma unroll
    for (int m = 0; m < 4; m++) {
      int row_b = row0 + wr * 64 + m * 16 + lg * 4;
#pragma unroll
      for (int n = 0; n < 4; n++) {
        int col = col0 + wc * 64 + n * 16 + l15;
        int cw = (MODE == 0) ? col : (col - 2048);
#pragma unroll
        for (int j = 0; j < 4; j++) {
          Cf[(size_t)(row_b + j) * ldc + cw] = acc[m][n][j];
        }
      }
    }
  } else {
#pragma unroll
    for (int m = 0; m < 4; m++) {
      int row_b = row0 + wr * 64 + m * 16 + lg * 4;
#pragma unroll
      for (int n = 0; n < 4; n++) {
        int col = col0 + wc * 64 + n * 16 + l15;
        int h = col >> 7, d = col & 127;
#pragma unroll
        for (int j = 0; j < 4; j++) {
          int row = row_b + j;
          int b = row >> 11, nn = row & 2047;
          Cb[(((size_t)b * 16 + h) * 2048 + nn) * 128 + d] = f2bf(acc[m][n][j]);
        }
      }
    }
  }
}

// ---------- merged q+small GEMM ----------
__global__ __launch_bounds__(256) void gemm_q(const unsigned short* __restrict__ A,
                                              const unsigned short* __restrict__ B,
                                              float* __restrict__ small_out,
                                              unsigned short* __restrict__ q_r) {
  gemm_body<1>(A, B, small_out, q_r, 2048, 384, (int)(blockIdx.y * 19 + blockIdx.x), 19, 76);
}

// ---------- out GEMM ----------
__global__ __launch_bounds__(256) void gemm_out(const unsigned short* __restrict__ A,
                                                const unsigned short* __restrict__ B,
                                                float* __restrict__ C) {
  gemm_body<0>(A, B, C, nullptr, 2048, 2048, (int)(blockIdx.y * 16 + blockIdx.x), 16, 64);
}

// ---------- scan v3: 64 blocks (b,ch), 256 thr x 8 toks, shfl wave-scan ----------
__global__ __launch_bounds__(256) void scan_kernel(const float* __restrict__ lsg_t,
                                                   const float* __restrict__ so,
                                                   float* __restrict__ khvh) {
  int b = blockIdx.x >> 5, ch = blockIdx.x & 31;
  int t = threadIdx.x, lane = t & 63, wv = t >> 6;
  const float* L = lsg_t + ((size_t)(b * 32 + ch)) * 2048 + t * 8;
  float ls[8], v[8];
  float4 a = *(const float4*)L, c = *(const float4*)(L + 4);
  ls[0] = a.x; ls[1] = a.y; ls[2] = a.z; ls[3] = a.w;
  ls[4] = c.x; ls[5] = c.y; ls[6] = c.z; ls[7] = c.w;
  const float* V = so + ((size_t)(b * 2048 + t * 8)) * 384 + 256 + ch;
#pragma unroll
  for (int j = 0; j < 8; j++) v[j] = V[(size_t)j * 384];
  float run = 0.f;
#pragma unroll
  for (int j = 0; j < 8; j++) run += ls[j];
  float incl = run;
#pragma unroll
  for (int off = 1; off < 64; off <<= 1) {
    float nv = __shfl_up(incl, off);
    if (lane >= off) incl += nv;
  }
  __shared__ float ws[2][4];
  if (lane == 63) ws[0][wv] = incl;
  __syncthreads();
  float wbase = 0.f;
#pragma unroll
  for (int w = 0; w < 4; w++) wbase += (w < wv) ? ws[0][w] : 0.f;
  float baseA = wbase + incl - run;
  float lf = baseA, s = 0.f;
#pragma unroll
  for (int j = 0; j < 8; j++) { s += v[j] * __expf(lf); lf += ls[j]; }
  float incl2 = s;
#pragma unroll
  for (int off = 1; off < 64; off <<= 1) {
    float nv = __shfl_up(incl2, off);
    if (lane >= off) incl2 += nv;
  }
  if (lane == 63) ws[1][wv] = incl2;
  __syncthreads();
  float wbase2 = 0.f;
#pragma unroll
  for (int w = 0; w < 4; w++) wbase2 += (w < wv) ? ws[1][w] : 0.f;
  float base2 = wbase2 + incl2 - s;
  lf = baseA; s = base2;
  float* O = khvh + ((size_t)(b * 2048 + t * 8)) * 32 + ch;
#pragma unroll
  for (int j = 0; j < 8; j++) { s += v[j] * __expf(lf); lf += ls[j]; O[(size_t)j * 32] = s; }
}

// ---------- build_kv2: merged k_r build (+rope) and v_t transposed build ----------
__global__ __launch_bounds__(256) void build_kv2(const float* __restrict__ so,
                                                 const float* __restrict__ khvh,
                                                 const float2* __restrict__ cs,
                                                 unsigned short* __restrict__ k_r,
                                                 unsigned short* __restrict__ v_t) {
  int ntb = blockIdx.x, bh = blockIdx.y;
  int b = bh >> 4, h = bh & 15;
  int tok0 = b * 2048 + ntb * 64;
  int n0 = ntb * 64;
  __shared__ float khs[64], vhs[64];
  __shared__ unsigned short Vt_s[64 * 132];
  int t = threadIdx.x;
  if (t < 64) {
    khs[t] = khvh[(size_t)(tok0 + t) * 32 + h];
    vhs[t] = khvh[(size_t)(tok0 + t) * 32 + 16 + h];
  }
  __syncthreads();
#pragma unroll
  for (int c = 0; c < 4; c++) {
    int idx = c * 256 + t;
    int r = idx >> 4, q4 = (idx & 15) * 4;
    const float* sop = so + (size_t)(tok0 + r) * 384;
    float4 k1 = *(const float4*)(sop + q4);
    float4 k2 = *(const float4*)(sop + 64 + q4);
    float kh = khs[r];
    int n = n0 + r;
    union { unsigned short u[4]; uint2 v2; } o1, o2;
#pragma unroll
    for (int j = 0; j < 4; j++) {
      float2 cc = cs[(n << 6) + q4 + j];
      float av = ((const float*)&k1)[j], bv = ((const float*)&k2)[j];
      o1.u[j] = f2bf((av * cc.x - bv * cc.y) * kh);
      o2.u[j] = f2bf((bv * cc.x + av * cc.y) * kh);
    }
    size_t off = ((size_t)bh * 2048 + n) * 128 + q4;
    *(uint2*)(k_r + off) = o1.v2;
    *(uint2*)(k_r + off + 64) = o2.v2;
  }
#pragma unroll
  for (int c = 0; c < 8; c++) {
    int idx = c * 256 + t;
    int r = idx >> 5, d4 = (idx & 31) * 4;
    const float* sop = so + (size_t)(tok0 + r) * 384 + 128;
    float4 v = *(const float4*)(sop + d4);
    float vh = vhs[r];
    union { unsigned short u[4]; uint2 v2; } ov;
#pragma unroll
    for (int j = 0; j < 4; j++) ov.u[j] = f2bf(((const float*)&v)[j] * vh);
    *(uint2*)&Vt_s[r * 132 + d4] = ov.v2;
  }
  __syncthreads();
#pragma unroll
  for (int c = 0; c < 4; c++) {
    int idx = c * 256 + t;
    int d = idx >> 3, c8 = (idx & 7) * 8;
    union { unsigned short u[8]; bf16x8 v; } o;
#pragma unroll
    for (int j = 0; j < 8; j++) o.u[j] = Vt_s[(c8 + j) * 132 + d];
    *(bf16x8*)(v_t + ((size_t)bh * 128 + d) * 2048 + n0 + c8) = o.v;
  }
}

// ---------- flash attention v4.2 (unchanged) ----------
__global__ __launch_bounds__(256, 2) void flash_attn(const unsigned short* __restrict__ q_r,
                                                     const unsigned short* __restrict__ k_r,
                                                     const unsigned short* __restrict__ v_t,
                                                     const float2* __restrict__ cs,
                                                     unsigned short* __restrict__ o) {
  int lin = blockIdx.y * 16 + blockIdx.x;
  int swz = (lin & 7) * 64 + (lin >> 3);
  int bx = swz & 15, bh = swz >> 4;
  const unsigned short* Kg = k_r + (size_t)bh * 2048 * 128;
  const unsigned short* Vtg = v_t + (size_t)bh * 128 * 2048;
  __shared__ unsigned short Ks[2][64 * 128];
  __shared__ unsigned short VTs[2][128 * 64];
  __shared__ unsigned short Ps[4][16 * 72];
  int tid = threadIdx.x, wave = tid >> 6, lane = tid & 63, l15 = lane & 15, lg = lane >> 4;
  int sw = (l15 & 7) * 8;
  int b = bh >> 4, h = bh & 15;

  union { unsigned short u[8]; bf16x8 v; } onesu;
#pragma unroll
  for (int j = 0; j < 8; j++) onesu.u[j] = 0x3F80;
  const bf16x8 ones = onesu.v;

  int qtA = bx, qtB = 31 - bx;
  int qt = qtA;

  bf16x8 qf[4];
#define LOAD_Q()                                                                                   \
  {                                                                                                \
    const unsigned short* Qg = q_r + ((size_t)bh * 2048 + qt * 64) * 128;                          \
    int n = qt * 64 + wave * 16 + l15;                                                             \
    union { unsigned short u[8]; bf16x8 v; } r0, r1, r2, r3;                                       \
    r0.v = *(const bf16x8*)(Qg + (wave * 16 + l15) * 128 + 0 * 32 + lg * 8);                       \
    r1.v = *(const bf16x8*)(Qg + (wave * 16 + l15) * 128 + 1 * 32 + lg * 8);                       \
    r2.v = *(const bf16x8*)(Qg + (wave * 16 + l15) * 128 + 2 * 32 + lg * 8);                       \
    r3.v = *(const bf16x8*)(Qg + (wave * 16 + l15) * 128 + 3 * 32 + lg * 8);                       \
    union { unsigned short u[8]; bf16x8 v; } o0, o1, o2, o3;                                       \
    _Pragma("unroll") for (int j = 0; j < 8; j++) {                                                \
      float2 c0 = cs[(n << 6) + 0 * 32 + lg * 8 + j];                                              \
      float t1 = bf2f(r0.u[j]), t2 = bf2f(r2.u[j]);                                                \
      o0.u[j] = f2bf(t1 * c0.x - t2 * c0.y);                                                       \
      o2.u[j] = f2bf(t2 * c0.x + t1 * c0.y);                                                       \
      float2 c1 = cs[(n << 6) + 1 * 32 + lg * 8 + j];                                              \
      float s1 = bf2f(r1.u[j]), s2 = bf2f(r3.u[j]);                                                \
      o1.u[j] = f2bf(s1 * c1.x - s2 * c1.y);                                                       \
      o3.u[j] = f2bf(s2 * c1.x + s1 * c1.y);                                                       \
    }                                                                                              \
    qf[0] = o0.v; qf[1] = o1.v; qf[2] = o2.v; qf[3] = o3.v;                                        \
  }

  LOAD_Q();

  float m_r[4], l_r[4];
  f32x4 oacc[8];
#pragma unroll
  for (int j = 0; j < 4; j++) { m_r[j] = -INFINITY; l_r[j] = 0.f; }
#pragma unroll
  for (int db = 0; db < 8; db++) oacc[db] = (f32x4){0.f, 0.f, 0.f, 0.f};

  const float kscale = 0.12753102f;  // (1/sqrt(128)) * log2(e)
  const float THR = 11.0f;

#define STAGE(kt, bsel)                                                                           \
  {                                                                                               \
    int kti = (kt);                                                                               \
    int bs = (bsel);                                                                              \
    _Pragma("unroll") for (int c = 0; c < 4; c++) {                                               \
      int s = c * 256 + tid;                                                                      \
      int kr = s >> 4, kc = ((s & 15) ^ (kr & 7)) * 8;                                            \
      __builtin_amdgcn_global_load_lds(                                                           \
          (const __attribute__((address_space(1))) void*)(Kg + (size_t)(kti * 64 + kr) * 128 + kc),\
          (__attribute__((address_space(3))) void*)(&Ks[bs][(c * 256 + wave * 64) * 8]), 16, 0, 0);\
      int vr = s >> 3, vc = ((s & 7) ^ (vr & 7)) * 8;                                             \
      __builtin_amdgcn_global_load_lds(                                                           \
          (const __attribute__((address_space(1))) void*)(Vtg + (size_t)vr * 2048 + kti * 64 + vc),\
          (__attribute__((address_space(3))) void*)(&VTs[bs][(c * 256 + wave * 64) * 8]), 16, 0, 0);\
    }                                                                                             \
  }

  STAGE(0, 0);
  __syncthreads();

  for (int s = 0; s < 33; ++s) {
    int nb = s & 1;
    if (s + 1 < 33) {
      int nk = (s + 1 <= qtA) ? (s + 1) : (s + 1 - (qtA + 1));
      STAGE(nk, nb ^ 1);
    }
    int kt = (s <= qtA) ? s : (s - (qtA + 1));
    bool diag = (s == qtA) || (s == 32);
    int qrow0 = qt * 64 + wave * 16 + lg * 4;

    f32x4 sc[4];
#pragma unroll
    for (int cb = 0; cb < 4; cb++) sc[cb] = (f32x4){0.f, 0.f, 0.f, 0.f};
    __builtin_amdgcn_s_setprio(1);
#pragma unroll
    for (int kk = 0; kk < 4; kk++) {
#pragma unroll
      for (int cb = 0; cb < 4; cb++) {
        bf16x8 kf = *(const bf16x8*)&Ks[nb][(cb * 16 + l15) * 128 + ((kk * 32 + lg * 8) ^ sw)];
        sc[cb] = MFMA16(qf[kk], kf, sc[cb]);
      }
    }
    __builtin_amdgcn_s_setprio(0);
    if (diag) {
#pragma unroll
      for (int cb = 0; cb < 4; cb++) {
        int col = kt * 64 + cb * 16 + l15;
#pragma unroll
        for (int j = 0; j < 4; j++) {
          float v = sc[cb][j] * kscale;
          if (col > qrow0 + j) v = -INFINITY;
          sc[cb][j] = v;
        }
      }
    } else {
#pragma unroll
      for (int cb = 0; cb < 4; cb++)
#pragma unroll
        for (int j = 0; j < 4; j++) sc[cb][j] *= kscale;
    }
    float pm[4];
#pragma unroll
    for (int j = 0; j < 4; j++)
      pm[j] = fmaxf(fmaxf(sc[0][j], sc[1][j]), fmaxf(sc[2][j], sc[3][j]));
    bool grow = !__all((pm[0] <= m_r[0] + THR) & (pm[1] <= m_r[1] + THR) &
                       (pm[2] <= m_r[2] + THR) & (pm[3] <= m_r[3] + THR));
    if (grow) {
#pragma unroll
      for (int off = 1; off < 16; off <<= 1) {
#pragma unroll
        for (int j = 0; j < 4; j++) pm[j] = fmaxf(pm[j], __shfl_xor(pm[j], off));
      }
#pragma unroll
      for (int j = 0; j < 4; j++) {
        float mn = fmaxf(m_r[j], pm[j]);
        float corr = fast_exp2(m_r[j] - mn);
        m_r[j] = mn;
        l_r[j] *= corr;
#pragma unroll
        for (int db = 0; db < 8; db++) oacc[db][j] *= corr;
      }
    }
#pragma unroll
    for (int cb = 0; cb < 4; cb++)
#pragma unroll
      for (int j = 0; j < 4; j++)
        Ps[wave][(lg * 4 + j) * 72 + cb * 16 + l15] = f2bf(fast_exp2(sc[cb][j] - m_r[j]));
    f32x4 sacc = (f32x4){0.f, 0.f, 0.f, 0.f};
    __builtin_amdgcn_s_setprio(1);
#pragma unroll
    for (int kc = 0; kc < 2; kc++) {
      bf16x8 pa = *(const bf16x8*)&Ps[wave][l15 * 72 + kc * 32 + lg * 8];
      sacc = MFMA16(pa, ones, sacc);
#pragma unroll
      for (int db = 0; db < 8; db++) {
        bf16x8 vb = *(const bf16x8*)&VTs[nb][(db * 16 + l15) * 64 + ((kc * 32 + lg * 8) ^ sw)];
        oacc[db] = MFMA16(pa, vb, oacc[db]);
      }
    }
    __builtin_amdgcn_s_setprio(0);
#pragma unroll
    for (int j = 0; j < 4; j++) l_r[j] += sacc[j];
    __syncthreads();

    if (s == qtA) {
      int qrow_e = qt * 64 + wave * 16 + lg * 4;
#pragma unroll
      for (int db = 0; db < 8; db++) {
        int d = db * 16 + l15;
#pragma unroll
        for (int j = 0; j < 4; j++) {
          float val = oacc[db][j] / l_r[j];
          o[((size_t)(b * 2048 + qrow_e + j)) * 2048 + h * 128 + d] = f2bf(val);
        }
      }
      qt = qtB;
      LOAD_Q();
#pragma unroll
      for (int j = 0; j < 4; j++) { m_r[j] = -INFINITY; l_r[j] = 0.f; }
#pragma unroll
      for (int db = 0; db < 8; db++) oacc[db] = (f32x4){0.f, 0.f, 0.f, 0.f};
    }
  }
  int qrow_e = qt * 64 + wave * 16 + lg * 4;
#pragma unroll
  for (int db = 0; db < 8; db++) {
    int d = db * 16 + l15;
#pragma unroll
    for (int j = 0; j < 4; j++) {
      float val = oacc[db][j] / l_r[j];
      o[((size_t)(b * 2048 + qrow_e + j)) * 2048 + h * 128 + d] = f2bf(val);
    }
  }
#undef STAGE
#undef LOAD_Q
}

// ---------- host launch ----------
extern "C" void kernel_launch(void* const* d_in, const int* in_sizes, int n_in,
                              void* d_out, int out_size, void* d_ws, size_t ws_size,
                              hipStream_t stream) {
  (void)in_sizes; (void)n_in; (void)out_size; (void)ws_size;
  const float* x    = (const float*)d_in[0];
  const float* Wq   = (const float*)d_in[1];
  const float* Wkv  = (const float*)d_in[2];
  const float* Wkvh = (const float*)d_in[3];
  const float* Wg   = (const float*)d_in[4];
  const float* Wout = (const float*)d_in[5];
  float* out = (float*)d_out;

  char* ws = (char*)d_ws;
  size_t off = 0;
  auto alloc = [&](size_t bytes) -> void* {
    void* p = ws + off;
    off += (bytes + 255) & ~(size_t)255;
    return p;
  };
  unsigned short* x_bf    = (unsigned short*)alloc(4096ull * 2048 * 2);
  unsigned short* wq_bf   = (unsigned short*)alloc(2048ull * 2048 * 2);   // must stay adjacent to wsm_bf
  unsigned short* wsm_bf  = (unsigned short*)alloc(384ull * 2048 * 2);    // rows 2048..2431 of merged B
  unsigned short* wout_bf = (unsigned short*)alloc(2048ull * 2048 * 2);
  unsigned short* q_r     = (unsigned short*)alloc(4096ull * 2048 * 2);
  unsigned short* k_r     = (unsigned short*)alloc(4096ull * 2048 * 2);
  unsigned short* o_bf    = (unsigned short*)alloc(4096ull * 2048 * 2);
  float* small_out        = (float*)alloc(4096ull * 384 * 4);
  float* lsg_t            = (float*)alloc(64ull * 2048 * 4);
  float* khvh             = (float*)alloc(4096ull * 32 * 4);
  float2* cs              = (float2*)alloc(2048ull * 64 * 8);
  float* wgt              = (float*)alloc(2048ull * 32 * 4);
  unsigned short* v_t     = x_bf;  // x_bf dead after merged GEMM

  prep<<<9344, 256, 0, stream>>>(x, Wq, Wout, Wkv, Wkvh, Wg, x_bf, wq_bf, wout_bf, wsm_bf, cs, wgt);
  gproj<<<512, 256, 0, stream>>>(x, wgt, lsg_t);
  gemm_q<<<dim3(19, 32), 256, 0, stream>>>(x_bf, wq_bf, small_out, q_r);
  scan_kernel<<<64, 256, 0, stream>>>(lsg_t, small_out, khvh);
  build_kv2<<<dim3(32, 32), 256, 0, stream>>>(small_out, khvh, cs, k_r, v_t);
  flash_attn<<<dim3(16, 32), 256, 0, stream>>>(q_r, k_r, v_t, cs, o_bf);
  gemm_out<<<dim3(16, 32), 256, 0, stream>>>(o_bf, wout_bf, out);
}